// Round 1
// baseline (207.201 us; speedup 1.0000x reference)
//
#include <hip/hip_runtime.h>

// Problem constants (B,N,D fixed by the reference)
#define BB   64
#define NN   2048
#define DD   128
#define CHUNKS 16           // blocks per batch item
#define ROWS_PER_BLOCK 128  // neighbors per block
#define STAGE_ROWS 64       // rows staged in LDS at a time
#define LDSPAD 132          // 128 + 4 floats pad (keeps 16B alignment, breaks bank stride)

// ws layout: sprime[64][128] f32 at byte 0; denom[64] f32 at byte 32768.

__global__ __launch_bounds__(256) void aegis_main(
    const float* __restrict__ e_i, const float* __restrict__ e_j,
    const float* __restrict__ imp, const float* __restrict__ Wq,
    const float* __restrict__ Wk,  const float* __restrict__ omega,
    float* __restrict__ sprime, float* __restrict__ denom)
{
    __shared__ float Et[STAGE_ROWS][LDSPAD];
    __shared__ float qs[DD];
    __shared__ float oms[DD];
    __shared__ float eis[DD];
    __shared__ float sig[STAGE_ROWS][4];
    __shared__ float wrow[STAGE_ROWS];
    __shared__ float esbuf[STAGE_ROWS];
    __shared__ float scol[2][DD];
    __shared__ float sacc[DD];

    const int t = threadIdx.x;
    const int blk = blockIdx.x;
    const int b = blk >> 4;       // 16 chunks per batch
    const int chunk = blk & 15;
    const int row0 = chunk * ROWS_PER_BLOCK;

    // ---- per-block q[b] = e_i[b] @ Wq.T (redundant per chunk; 16K FMA, ~0.5% cost) ----
    if (t < DD) { eis[t] = e_i[b * DD + t]; oms[t] = omega[t]; sacc[t] = 0.f; }
    __syncthreads();
    if (t < DD) {
        float acc = 0.f;
        const float4* wqr = reinterpret_cast<const float4*>(Wq + t * DD);
        const float4* eiv = reinterpret_cast<const float4*>(eis);
        #pragma unroll 8
        for (int d4 = 0; d4 < DD / 4; ++d4) {
            float4 w = wqr[d4]; float4 e = eiv[d4];
            acc = fmaf(e.x, w.x, acc); acc = fmaf(e.y, w.y, acc);
            acc = fmaf(e.z, w.z, acc); acc = fmaf(e.w, w.w, acc);
        }
        qs[t] = acc;
    }

    float den_local = 0.f;

    // wave-uniform e-strip: wave w handles e in [32w, 32w+32); lane = row
    const int wvu = __builtin_amdgcn_readfirstlane(t >> 6);  // force SGPR
    const int r   = t & 63;
    const int e0  = wvu * 32;

    for (int s = 0; s < 2; ++s) {
        __syncthreads();  // protect Et from previous stage's readers
        // ---- stage 64 rows x 128 f32, coalesced float4 ----
        {
            const float4* src = reinterpret_cast<const float4*>(
                e_j + ((size_t)(b * NN + row0 + s * STAGE_ROWS)) * DD);
            #pragma unroll
            for (int i = 0; i < 8; ++i) {
                int idx = t + i * 256;      // 2048 float4 total
                int rr = idx >> 5;          // 32 float4 per row
                int cc = idx & 31;
                float4 v = src[idx];
                *reinterpret_cast<float4*>(&Et[rr][cc * 4]) = v;
            }
        }
        __syncthreads();

        // ---- K-GEMM strip: k[r][e0..e0+31], W_k via wave-uniform scalar loads ----
        float acc[32];
        #pragma unroll
        for (int e = 0; e < 32; ++e) acc[e] = 0.f;
        #pragma unroll 2
        for (int d0 = 0; d0 < DD; d0 += 4) {
            float4 ev = *reinterpret_cast<const float4*>(&Et[r][d0]);
            #pragma unroll
            for (int dd = 0; dd < 4; ++dd) {
                float ed = (&ev.x)[dd];
                #pragma unroll
                for (int e = 0; e < 32; ++e)
                    acc[e] = fmaf(ed, Wk[(e0 + e) * DD + d0 + dd], acc[e]);
            }
        }

        // ---- sigma partial: sum omega_e * tanh(q_e + k_e) over this strip ----
        float p = 0.f;
        #pragma unroll 8
        for (int e = 0; e < 32; ++e) {
            float x = qs[e0 + e] + acc[e];
            p = fmaf(oms[e0 + e], tanhf(x), p);
        }
        sig[r][wvu] = p;
        __syncthreads();

        if (t < STAGE_ROWS) {
            float sg = sig[t][0] + sig[t][1] + sig[t][2] + sig[t][3];
            float es = expf(sg);
            esbuf[t] = es;
            wrow[t]  = es * imp[b * NN + row0 + s * STAGE_ROWS + t];
        }
        __syncthreads();

        // ---- weighted column sum: s'[d] += sum_r wrow[r] * Et[r][d] ----
        {
            int d = t & 127, hf = t >> 7;
            float part = 0.f;
            #pragma unroll 8
            for (int rr = hf * 32; rr < hf * 32 + 32; ++rr)
                part = fmaf(wrow[rr], Et[rr][d], part);
            scol[hf][d] = part;
        }
        __syncthreads();
        if (t < DD) sacc[t] += scol[0][t] + scol[1][t];
        if (t == 0) {
            float ds = 0.f;
            for (int rr = 0; rr < STAGE_ROWS; ++rr) ds += esbuf[rr];
            den_local += ds;
        }
    }
    __syncthreads();
    if (t < DD) atomicAdd(&sprime[b * DD + t], sacc[t]);
    if (t == 0) atomicAdd(&denom[b], den_local);
}

// A_l = (s'/denom) @ Wv.T ; A_lk[l,k] = R[l,k]*A_l[k] ; out = [A_l | A_lk | A_l]
__global__ __launch_bounds__(256) void aegis_epi(
    const float* __restrict__ sprime, const float* __restrict__ denomv,
    const float* __restrict__ Wv, const float* __restrict__ R,
    float* __restrict__ out)
{
    __shared__ float sn[DD];
    __shared__ float alred[DD][2];
    __shared__ float al[DD];
    const int t = threadIdx.x;
    const int b = blockIdx.x;

    if (t < DD) sn[t] = sprime[b * DD + t] / (denomv[b] + 1e-9f);
    __syncthreads();
    {
        int l = t >> 1, h = t & 1;
        const float4* wvr = reinterpret_cast<const float4*>(Wv + l * DD + h * 64);
        const float4* snp = reinterpret_cast<const float4*>(sn + h * 64);
        float acc = 0.f;
        #pragma unroll 8
        for (int d4 = 0; d4 < 16; ++d4) {
            float4 w = wvr[d4]; float4 e = snp[d4];
            acc = fmaf(e.x, w.x, acc); acc = fmaf(e.y, w.y, acc);
            acc = fmaf(e.z, w.z, acc); acc = fmaf(e.w, w.w, acc);
        }
        alred[l][h] = acc;
    }
    __syncthreads();
    if (t < DD) {
        float v = alred[t][0] + alred[t][1];
        al[t] = v;
        out[b * DD + t] = v;                          // A_l (output 0)
        out[8192 + 1048576 + b * DD + t] = v;         // A_l (output 2)
    }
    __syncthreads();
    float* outk = out + 8192 + (size_t)b * DD * DD;   // A_lk (output 1)
    #pragma unroll
    for (int i = 0; i < 64; ++i) {
        int idx = t + i * 256;
        outk[idx] = R[idx] * al[idx & 127];
    }
}

extern "C" void kernel_launch(void* const* d_in, const int* in_sizes, int n_in,
                              void* d_out, int out_size, void* d_ws, size_t ws_size,
                              hipStream_t stream) {
    const float* e_i  = (const float*)d_in[0];
    const float* e_j  = (const float*)d_in[1];
    const float* imp  = (const float*)d_in[2];
    const float* R    = (const float*)d_in[3];
    const float* Wq   = (const float*)d_in[4];
    const float* Wk   = (const float*)d_in[5];
    const float* Wv   = (const float*)d_in[6];
    const float* om   = (const float*)d_in[7];

    float* sprime = (float*)d_ws;
    float* denom  = (float*)((char*)d_ws + 32768);

    hipMemsetAsync(d_ws, 0, 32768 + 256, stream);
    aegis_main<<<dim3(BB * CHUNKS), dim3(256), 0, stream>>>(
        e_i, e_j, imp, Wq, Wk, om, sprime, denom);
    aegis_epi<<<dim3(BB), dim3(256), 0, stream>>>(sprime, denom, Wv, R, (float*)d_out);
}

// Round 3
// 156.060 us; speedup vs baseline: 1.3277x; 1.3277x over previous
//
#include <hip/hip_runtime.h>
#include <stdint.h>

#define BB 64
#define NN 2048
#define DD 128
#define ROWS 64           // neighbor rows per block
#define PADB 136          // bf16 elements per LDS row (136*2=272 B, 16B-aligned, breaks bank stride)

typedef __attribute__((ext_vector_type(8))) short short8;
typedef __attribute__((ext_vector_type(4))) float f32x4;

__device__ __forceinline__ unsigned short f2bf_rtne(float x) {
    union { float f; unsigned int u; } v; v.f = x;
    unsigned int r = v.u + 0x7fffu + ((v.u >> 16) & 1u);
    return (unsigned short)(r >> 16);
}
__device__ __forceinline__ float bf2f(unsigned short h) {
    union { unsigned int u; float f; } v; v.u = ((unsigned int)h) << 16;
    return v.f;
}
__device__ __forceinline__ float tanh_fast(float x) {
    float ax = fabsf(x);
    float e  = __expf(-2.f * ax);          // exp underflows to 0 for big ax -> t=1
    float t  = (1.f - e) / (1.f + e);
    return copysignf(t, x);
}

// ---------------- prep: q[b,e] = sum_d e_i[b,d] * Wq[e,d] ----------------
__global__ __launch_bounds__(128) void aegis_prep(
    const float* __restrict__ e_i, const float* __restrict__ Wq,
    float* __restrict__ qbuf)
{
    __shared__ float eis[DD];
    const int t = threadIdx.x, b = blockIdx.x;
    eis[t] = e_i[b * DD + t];
    __syncthreads();
    float acc = 0.f;
    const float4* wr = reinterpret_cast<const float4*>(Wq + t * DD);
    const float4* ev = reinterpret_cast<const float4*>(eis);
    #pragma unroll 8
    for (int i = 0; i < 32; ++i) {
        float4 w = wr[i], e = ev[i];
        acc = fmaf(w.x, e.x, acc); acc = fmaf(w.y, e.y, acc);
        acc = fmaf(w.z, e.z, acc); acc = fmaf(w.w, e.w, acc);
    }
    qbuf[b * DD + t] = acc;
}

// ---------------- main: MFMA K-GEMM + sigma + exp + weighted colsum ----------------
__global__ __launch_bounds__(256) void aegis_main(
    const float* __restrict__ e_j, const float* __restrict__ imp,
    const float* __restrict__ Wk,  const float* __restrict__ omega,
    const float* __restrict__ qbuf,
    float* __restrict__ sprime, float* __restrict__ denom)
{
    __shared__ unsigned short Ehi[ROWS][PADB];
    __shared__ unsigned short Elo[ROWS][PADB];
    __shared__ float sig[ROWS][4];
    __shared__ float wrow[ROWS];
    __shared__ float scol[DD];

    const int t     = threadIdx.x;
    const int blk   = blockIdx.x;
    const int b     = blk >> 5;          // 32 blocks per batch item
    const int chunk = blk & 31;
    const int row0  = chunk * ROWS;

    const int lane = t & 63;
    const int w    = t >> 6;             // wave id 0..3 -> col strip [32w, 32w+32)
    const int lr   = lane & 15;
    const int lg   = lane >> 4;          // 0..3

    // ---- B fragments (Wk strip, hi/lo split), held in VGPRs for the whole kernel ----
    // B layout (16x16x32): lane holds col = lr, k-rows = lg*8 + j  (k block ks*32)
    // B[k][e] = WkT[k][e] = Wk[e][k] -> 8 consecutive floats along a Wk row.
    short8 Bhi[2][4], Blo[2][4];
    #pragma unroll
    for (int ct = 0; ct < 2; ++ct) {
        const int e = 32 * w + 16 * ct + lr;
        const float* wr = Wk + e * DD + lg * 8;
        #pragma unroll
        for (int ks = 0; ks < 4; ++ks) {
            float4 x0 = *reinterpret_cast<const float4*>(wr + ks * 32);
            float4 x1 = *reinterpret_cast<const float4*>(wr + ks * 32 + 4);
            float xs[8] = {x0.x, x0.y, x0.z, x0.w, x1.x, x1.y, x1.z, x1.w};
            short8 h, l;
            #pragma unroll
            for (int j = 0; j < 8; ++j) {
                unsigned short hb = f2bf_rtne(xs[j]);
                float rem = xs[j] - bf2f(hb);
                h[j] = (short)hb;
                l[j] = (short)f2bf_rtne(rem);
            }
            Bhi[ct][ks] = h; Blo[ct][ks] = l;
        }
    }

    // ---- stage 64 rows of e_j as bf16 hi/lo into LDS (convert once per element) ----
    {
        const float4* src = reinterpret_cast<const float4*>(
            e_j + ((size_t)(b * NN + row0)) * DD);
        #pragma unroll
        for (int i = 0; i < 8; ++i) {
            int idx = t + i * 256;       // 0..2047 float4 slots (64 rows x 32)
            int rr  = idx >> 5;
            int cc  = (idx & 31) * 4;
            float4 v = src[idx];
            float xs[4] = {v.x, v.y, v.z, v.w};
            unsigned short hs[4], ls[4];
            #pragma unroll
            for (int j = 0; j < 4; ++j) {
                hs[j] = f2bf_rtne(xs[j]);
                ls[j] = f2bf_rtne(xs[j] - bf2f(hs[j]));
            }
            uint2 ph, pl;
            ph.x = (unsigned)hs[0] | ((unsigned)hs[1] << 16);
            ph.y = (unsigned)hs[2] | ((unsigned)hs[3] << 16);
            pl.x = (unsigned)ls[0] | ((unsigned)ls[1] << 16);
            pl.y = (unsigned)ls[2] | ((unsigned)ls[3] << 16);
            *reinterpret_cast<uint2*>(&Ehi[rr][cc]) = ph;
            *reinterpret_cast<uint2*>(&Elo[rr][cc]) = pl;
        }
    }

    // per-lane q / omega for this lane's two output columns
    float qv[2], ov[2];
    #pragma unroll
    for (int ct = 0; ct < 2; ++ct) {
        int c = 32 * w + 16 * ct + lr;
        qv[ct] = qbuf[b * DD + c];
        ov[ct] = omega[c];
    }
    __syncthreads();

    // ---- K-GEMM via MFMA (3-term bf16 split) + sigma partials ----
    #pragma unroll 1
    for (int rt = 0; rt < 4; ++rt) {
        f32x4 acc0 = {0.f, 0.f, 0.f, 0.f};
        f32x4 acc1 = {0.f, 0.f, 0.f, 0.f};
        #pragma unroll
        for (int ks = 0; ks < 4; ++ks) {
            // A layout: lane holds row = lr, k-cols = lg*8 + j
            const int arow = rt * 16 + lr;
            short8 ah = *reinterpret_cast<const short8*>(&Ehi[arow][ks * 32 + lg * 8]);
            short8 al = *reinterpret_cast<const short8*>(&Elo[arow][ks * 32 + lg * 8]);
            acc0 = __builtin_amdgcn_mfma_f32_16x16x32_bf16(ah, Bhi[0][ks], acc0, 0, 0, 0);
            acc1 = __builtin_amdgcn_mfma_f32_16x16x32_bf16(ah, Bhi[1][ks], acc1, 0, 0, 0);
            acc0 = __builtin_amdgcn_mfma_f32_16x16x32_bf16(ah, Blo[0][ks], acc0, 0, 0, 0);
            acc1 = __builtin_amdgcn_mfma_f32_16x16x32_bf16(ah, Blo[1][ks], acc1, 0, 0, 0);
            acc0 = __builtin_amdgcn_mfma_f32_16x16x32_bf16(al, Bhi[0][ks], acc0, 0, 0, 0);
            acc1 = __builtin_amdgcn_mfma_f32_16x16x32_bf16(al, Bhi[1][ks], acc1, 0, 0, 0);
        }
        // C layout: col = lr (per ct strip), rows = rt*16 + 4*lg + i
        float sp[4];
        #pragma unroll
        for (int i = 0; i < 4; ++i) {
            float x0 = qv[0] + acc0[i];
            float x1 = qv[1] + acc1[i];
            sp[i] = fmaf(ov[0], tanh_fast(x0), ov[1] * tanh_fast(x1));
        }
        #pragma unroll
        for (int m = 1; m < 16; m <<= 1) {
            #pragma unroll
            for (int i = 0; i < 4; ++i) sp[i] += __shfl_xor(sp[i], m);
        }
        if (lr == 0) {
            #pragma unroll
            for (int i = 0; i < 4; ++i) sig[rt * 16 + 4 * lg + i][w] = sp[i];
        }
    }
    __syncthreads();

    // ---- exp, weights, denominator (wave 0 only; full-wave shuffle reduce) ----
    if (t < ROWS) {
        float sg = sig[t][0] + sig[t][1] + sig[t][2] + sig[t][3];
        float es = __expf(sg);
        wrow[t]  = es * imp[b * NN + row0 + t];
        float d = es;
        #pragma unroll
        for (int m = 1; m < 64; m <<= 1) d += __shfl_xor(d, m);
        if (t == 0) atomicAdd(&denom[b], d);
    }
    __syncthreads();

    // ---- weighted column sum: s'[d] += sum_r wrow[r] * e_j[r][d] ----
    {
        int d  = t & 127;
        int hf = t >> 7;
        float part = 0.f;
        #pragma unroll
        for (int rr = hf * 32; rr < hf * 32 + 32; ++rr) {
            float ev = bf2f(Ehi[rr][d]) + bf2f(Elo[rr][d]);   // exact-ish fp32 reconstruction
            part = fmaf(wrow[rr], ev, part);
        }
        if (hf == 0) scol[d] = part;
        __syncthreads();
        if (hf == 1) atomicAdd(&sprime[b * DD + d], part + scol[d]);
    }
}

// ---------------- epi1: A_l = (s'/denom) @ Wv.T ; write outputs 0 and 2 ----------------
__global__ __launch_bounds__(128) void aegis_epi1(
    const float* __restrict__ sprime, const float* __restrict__ denomv,
    const float* __restrict__ Wv, float* __restrict__ out)
{
    __shared__ float sn[DD];
    const int t = threadIdx.x, b = blockIdx.x;
    sn[t] = sprime[b * DD + t] / (denomv[b] + 1e-9f);
    __syncthreads();
    float acc = 0.f;
    const float4* wr = reinterpret_cast<const float4*>(Wv + t * DD);
    const float4* sv = reinterpret_cast<const float4*>(sn);
    #pragma unroll 8
    for (int i = 0; i < 32; ++i) {
        float4 w = wr[i], e = sv[i];
        acc = fmaf(w.x, e.x, acc); acc = fmaf(w.y, e.y, acc);
        acc = fmaf(w.z, e.z, acc); acc = fmaf(w.w, e.w, acc);
    }
    out[b * DD + t] = acc;                          // A_l
    out[8192 + 1048576 + b * DD + t] = acc;         // A_l (output 2)
}

// ---------------- epi2: A_lk[b,l,k] = R[l,k] * A_l[b,k] ----------------
__global__ __launch_bounds__(256) void aegis_epi2(
    const float* __restrict__ R, const float* __restrict__ out0,
    float* __restrict__ outk)
{
    const int b  = blockIdx.x >> 2;
    const int sl = blockIdx.x & 3;
    const int t  = threadIdx.x;
    const float* al = out0 + b * DD;
    float4* dst = reinterpret_cast<float4*>(outk + (size_t)b * DD * DD + sl * 4096);
    const float4* rsrc = reinterpret_cast<const float4*>(R + sl * 4096);
    #pragma unroll
    for (int i = 0; i < 4; ++i) {
        int idx = t + i * 256;           // float4 index in slice (1024 per slice)
        float4 r = rsrc[idx];
        int k0 = (idx & 31) * 4;         // 32 float4 per 128-col row
        float4 o;
        o.x = r.x * al[k0];     o.y = r.y * al[k0 + 1];
        o.z = r.z * al[k0 + 2]; o.w = r.w * al[k0 + 3];
        dst[idx] = o;
    }
}

extern "C" void kernel_launch(void* const* d_in, const int* in_sizes, int n_in,
                              void* d_out, int out_size, void* d_ws, size_t ws_size,
                              hipStream_t stream) {
    const float* e_i = (const float*)d_in[0];
    const float* e_j = (const float*)d_in[1];
    const float* imp = (const float*)d_in[2];
    const float* R   = (const float*)d_in[3];
    const float* Wq  = (const float*)d_in[4];
    const float* Wk  = (const float*)d_in[5];
    const float* Wv  = (const float*)d_in[6];
    const float* om  = (const float*)d_in[7];

    float* out    = (float*)d_out;
    float* sprime = (float*)d_ws;                       // 8192 f32
    float* denom  = (float*)((char*)d_ws + 32768);      // 64 f32
    // q lives temporarily in d_out's A_lk region (overwritten by epi2 afterwards)
    float* qbuf   = out + 8192;

    hipMemsetAsync(d_ws, 0, 32768 + 256, stream);
    aegis_prep<<<dim3(BB), dim3(128), 0, stream>>>(e_i, Wq, qbuf);
    aegis_main<<<dim3(BB * 32), dim3(256), 0, stream>>>(
        e_j, imp, Wk, om, qbuf, sprime, denom);
    aegis_epi1<<<dim3(BB), dim3(128), 0, stream>>>(sprime, denom, Wv, out);
    aegis_epi2<<<dim3(BB * 4), dim3(256), 0, stream>>>(R, out, out + 8192);
}